// Round 4
// baseline (1244.594 us; speedup 1.0000x reference)
//
#include <hip/hip_runtime.h>
#include <cstdint>
#include <cstddef>

#define TT 256
#define NN 4096
#define CC 12
#define DD 256
#define KD 12
#define NB 16
#define NTH 512
#define HP 260   // dwords per packed-h row: 256 + 4 pad
#define XP 36    // dwords per packed-x row: 32 + 4 pad

typedef _Float16 half8 __attribute__((ext_vector_type(8)));
typedef float f32x4 __attribute__((ext_vector_type(4)));
#define MFMA __builtin_amdgcn_mfma_f32_16x16x32_f16

struct FalseC { static constexpr bool value = false; };
struct TrueC  { static constexpr bool value = true;  };

// LDS: 33,280 + 4,608 + 8,192 + 8,192 = 54,272 B
struct SM {
  unsigned hx[2][NB][HP];   // h as packed fp16 (hi | lo<<16), double-buffered
  unsigned xp[2][NB][XP];   // x_t / one-hot sos, packed fp16 pairs, cols 12..31 zero
  half8 wyhi[8][64];        // dec_Wy B-fragments, hi plane  [chunk][lane]
  half8 wylo[8][64];        // lo plane
};

__device__ __forceinline__ unsigned pack2(float v) {
  _Float16 h = (_Float16)v;
  float hf = (float)h;
  _Float16 l = (_Float16)(v - hf);
  unsigned short uh = __builtin_bit_cast(unsigned short, h);
  unsigned short ul = __builtin_bit_cast(unsigned short, l);
  return (unsigned)uh | ((unsigned)ul << 16);
}

__device__ __forceinline__ void split8(const float* w, half8& hi, half8& lo) {
  #pragma unroll
  for (int j = 0; j < 8; ++j) {
    _Float16 h = (_Float16)w[j];
    hi[j] = h;
    lo[j] = (_Float16)(w[j] - (float)h);
  }
}

__device__ __forceinline__ void unpack_hi(uint4 a, uint4 b, half8& hi) {
  unsigned h0 = __builtin_amdgcn_perm(a.y, a.x, 0x05040100u);
  unsigned h1 = __builtin_amdgcn_perm(a.w, a.z, 0x05040100u);
  unsigned h2 = __builtin_amdgcn_perm(b.y, b.x, 0x05040100u);
  unsigned h3 = __builtin_amdgcn_perm(b.w, b.z, 0x05040100u);
  hi = __builtin_bit_cast(half8, make_uint4(h0, h1, h2, h3));
}
__device__ __forceinline__ void unpack_lo(uint4 a, uint4 b, half8& lo) {
  unsigned l0 = __builtin_amdgcn_perm(a.y, a.x, 0x07060302u);
  unsigned l1 = __builtin_amdgcn_perm(a.w, a.z, 0x07060302u);
  unsigned l2 = __builtin_amdgcn_perm(b.y, b.x, 0x07060302u);
  unsigned l3 = __builtin_amdgcn_perm(b.w, b.z, 0x07060302u);
  lo = __builtin_bit_cast(half8, make_uint4(l0, l1, l2, l3));
}

__global__ __launch_bounds__(NTH, 2)
void seq2seq_kernel(const float* __restrict__ x,
                    const float* __restrict__ enc_Wx,
                    const float* __restrict__ enc_bx,
                    const float* __restrict__ enc_Wh,
                    const float* __restrict__ dec_Wx,
                    const float* __restrict__ dec_bx,
                    const float* __restrict__ dec_Wh,
                    const float* __restrict__ dec_Wy,
                    const float* __restrict__ dec_by,
                    float* __restrict__ out)
{
  __shared__ SM sm;
  const int tid  = (int)threadIdx.x;
  const int wid  = tid >> 6;
  const int lane = tid & 63;
  const int l15  = lane & 15;
  const int quad = lane >> 4;
  const int n0   = (int)blockIdx.x * NB;

  half8 Whi[2][8], Wlo[2][8];   // Wh B-fragments (AGPR-resident), persistent
  half8 Xhi[2], Xlo[2];         // Wx B-fragments (K=32 padded chunk)
  float bxr[2];

  auto loadWh = [&](const float* __restrict__ W) {
    #pragma unroll
    for (int tt = 0; tt < 2; ++tt) {
      const int n = (wid * 2 + tt) * 16 + l15;
      #pragma unroll
      for (int c = 0; c < 8; ++c) {
        float w[8];
        const float* p = W + (size_t)n * DD + c * 32 + quad * 8;
        *(float4*)&w[0] = *(const float4*)p;
        *(float4*)&w[4] = *(const float4*)(p + 4);
        split8(w, Whi[tt][c], Wlo[tt][c]);
      }
    }
  };
  auto loadWx = [&](const float* __restrict__ Wx) {
    #pragma unroll
    for (int tt = 0; tt < 2; ++tt) {
      const int n = (wid * 2 + tt) * 16 + l15;
      float w[8];
      #pragma unroll
      for (int j = 0; j < 8; ++j) {
        const int k = quad * 8 + j;
        w[j] = (k < CC) ? Wx[(size_t)n * CC + k] : 0.f;
      }
      split8(w, Xhi[tt], Xlo[tt]);
    }
  };
  auto loadBx = [&](const float* __restrict__ bx) {
    #pragma unroll
    for (int tt = 0; tt < 2; ++tt) bxr[tt] = bx[(wid * 2 + tt) * 16 + l15];
  };

  // One RNN step. DEC_c: tag type — decoder skips alo-of-x terms.
  auto stepA = [&](auto DEC_c, int rdbuf, int xslot, bool prefetch,
                   const float* __restrict__ xg) {
    constexpr bool DEC = decltype(DEC_c)::value;
    float pf[3];
    if (prefetch && wid == 1) {
      #pragma unroll
      for (int j = 0; j < 3; ++j) pf[j] = xg[lane + 64 * j];
    }
    // 4 independent accumulator chains: A = ahi-terms, B = alo/cross-terms
    f32x4 aA0 = {0.f,0.f,0.f,0.f}, aA1 = {0.f,0.f,0.f,0.f};
    f32x4 aB0 = {0.f,0.f,0.f,0.f}, aB1 = {0.f,0.f,0.f,0.f};

    // x-term first: operands already resident, fills MFMA pipe under h-reads
    {
      const uint4* p = (const uint4*)(&sm.xp[xslot][l15][0] + quad * 8);
      const uint4 a = p[0], b = p[1];
      half8 xhi;
      unpack_hi(a, b, xhi);
      aA0 = MFMA(xhi, Xhi[0], aA0, 0, 0, 0);
      aA1 = MFMA(xhi, Xhi[1], aA1, 0, 0, 0);
      if constexpr (!DEC) {
        half8 xlo;
        unpack_lo(a, b, xlo);
        aB0 = MFMA(xlo, Xhi[0], aB0, 0, 0, 0);
        aB1 = MFMA(xlo, Xhi[1], aB1, 0, 0, 0);
      }
      aB0 = MFMA(xhi, Xlo[0], aB0, 0, 0, 0);
      aB1 = MFMA(xhi, Xlo[1], aB1, 0, 0, 0);
    }
    const unsigned* hrow = &sm.hx[rdbuf][l15][0];   // A row m = lane&15
    #pragma unroll
    for (int c = 0; c < 8; ++c) {
      const uint4* p = (const uint4*)(hrow + c * 32 + quad * 8);
      const uint4 a = p[0], b = p[1];
      half8 ahi, alo;
      unpack_hi(a, b, ahi);
      unpack_lo(a, b, alo);
      aA0 = MFMA(ahi, Whi[0][c], aA0, 0, 0, 0);
      aA1 = MFMA(ahi, Whi[1][c], aA1, 0, 0, 0);
      aB0 = MFMA(alo, Whi[0][c], aB0, 0, 0, 0);
      aB1 = MFMA(alo, Whi[1][c], aB1, 0, 0, 0);
      aA0 = MFMA(ahi, Wlo[0][c], aA0, 0, 0, 0);
      aA1 = MFMA(ahi, Wlo[1][c], aA1, 0, 0, 0);
    }
    // epilogue: merge chains + bias + relu + pack, write new h
    #pragma unroll
    for (int r = 0; r < 4; ++r) {
      const int m = quad * 4 + r;
      const float v0 = fmaxf(aA0[r] + aB0[r] + bxr[0], 0.f);
      const float v1 = fmaxf(aA1[r] + aB1[r] + bxr[1], 0.f);
      sm.hx[rdbuf ^ 1][m][(wid * 2 + 0) * 16 + l15] = pack2(v0);
      sm.hx[rdbuf ^ 1][m][(wid * 2 + 1) * 16 + l15] = pack2(v1);
    }
    if (prefetch && wid == 1) {
      #pragma unroll
      for (int j = 0; j < 3; ++j) {
        const int i = lane + 64 * j;
        sm.xp[xslot ^ 1][i / CC][i % CC] = pack2(pf[j]);
      }
    }
  };

  // ---------------- init ----------------
  {
    unsigned* hz = &sm.hx[0][0][0];
    for (int i = tid; i < NB * HP; i += NTH) hz[i] = 0u;
    unsigned* xz = &sm.xp[0][0][0];
    for (int i = tid; i < 2 * NB * XP; i += NTH) xz[i] = 0u;
  }
  loadWh(enc_Wh);
  loadWx(enc_Wx);
  loadBx(enc_bx);
  __syncthreads();
  if (tid < NB * CC) {  // stage x_0
    const float v = x[(size_t)n0 * CC + tid];
    sm.xp[0][tid / CC][tid % CC] = pack2(v);
  }
  __syncthreads();

  // ---------------- encoder: 1 barrier/step ----------------
  for (int t = 0; t < TT; ++t) {
    stepA(FalseC{}, t & 1, t & 1, t + 1 < TT,
          x + ((size_t)(t + 1) * NN + n0) * CC);
    __syncthreads();
  }
  // encoder final h now in hx[0]

  // ---------------- decoder setup ----------------
  loadWh(dec_Wh);
  loadWx(dec_Wx);
  loadBx(dec_bx);
  const float byv = (l15 < KD) ? dec_by[l15] : 0.f;
  {  // stage dec_Wy fragments (B[k][n]: n=lane&15, k=chunk*32+quad*8+j)
    const int c = tid >> 6, ln = tid & 63, q2 = ln >> 4, n = ln & 15;
    float w[8];
    if (n < KD) {
      const float* p = dec_Wy + (size_t)n * DD + c * 32 + q2 * 8;
      *(float4*)&w[0] = *(const float4*)p;
      *(float4*)&w[4] = *(const float4*)(p + 4);
    } else {
      #pragma unroll
      for (int j = 0; j < 8; ++j) w[j] = 0.f;
    }
    half8 hi, lo;
    split8(w, hi, lo);
    sm.wyhi[c][ln] = hi;
    sm.wylo[c][ln] = lo;
  }
  if (wid == 0) {  // sos one-hot: column CC-2 = 10
    const int m2 = lane >> 2, cb = (lane & 3) * 8;
    #pragma unroll
    for (int j = 0; j < 8; ++j) sm.xp[0][m2][cb + j] = (cb + j == 10) ? 0x3C00u : 0u;
  }
  __syncthreads();

  // ---------------- decoder: 2 barriers/step ----------------
  for (int t = 0; t < TT; ++t) {
    stepA(TrueC{}, t & 1, 0, false, x);
    __syncthreads();
    if (wid == 0) {
      // y = h_new @ Wy^T + by  (single-wave MFMA, 3 independent chains)
      f32x4 yh = {0.f,0.f,0.f,0.f}, yl = {0.f,0.f,0.f,0.f}, yw = {0.f,0.f,0.f,0.f};
      const unsigned* hrow = &sm.hx[(t & 1) ^ 1][l15][0];
      #pragma unroll
      for (int c = 0; c < 8; ++c) {
        const uint4* p = (const uint4*)(hrow + c * 32 + quad * 8);
        const uint4 a = p[0], b = p[1];
        half8 ahi, alo;
        unpack_hi(a, b, ahi);
        unpack_lo(a, b, alo);
        const half8 bh = sm.wyhi[c][lane];
        const half8 bl = sm.wylo[c][lane];
        yh = MFMA(ahi, bh, yh, 0, 0, 0);
        yl = MFMA(alo, bh, yl, 0, 0, 0);
        yw = MFMA(ahi, bl, yw, 0, 0, 0);
      }
      float vr[4];
      int idxr[4];
      #pragma unroll
      for (int r = 0; r < 4; ++r) {
        const float yv = yh[r] + yl[r] + yw[r] + byv;
        const int m = quad * 4 + r;
        if (l15 < KD) out[((size_t)t * NN + n0 + m) * KD + l15] = yv;
        vr[r] = (l15 < KD) ? yv : -1e30f;
        idxr[r] = l15;
      }
      // argmax across the 16-lane n-groups, first-max tie-break (np semantics)
      #pragma unroll
      for (int d = 1; d < 16; d <<= 1) {
        #pragma unroll
        for (int r = 0; r < 4; ++r) {
          const float ov = __shfl_xor(vr[r], d);
          const int oi = __shfl_xor(idxr[r], d);
          const bool take = (ov > vr[r]) || (ov == vr[r] && oi < idxr[r]);
          vr[r] = take ? ov : vr[r];
          idxr[r] = take ? oi : idxr[r];
        }
      }
      // redistribute idx[m] to one-hot writers: writer lane covers row m2=lane>>2
      const int src = (lane >> 4) << 4;
      const int g0 = __shfl(idxr[0], src);
      const int g1 = __shfl(idxr[1], src);
      const int g2 = __shfl(idxr[2], src);
      const int g3 = __shfl(idxr[3], src);
      const int rr = (lane >> 2) & 3;
      const int myidx = rr == 0 ? g0 : rr == 1 ? g1 : rr == 2 ? g2 : g3;
      const int m2 = lane >> 2, cb = (lane & 3) * 8;
      #pragma unroll
      for (int j = 0; j < 8; ++j)
        sm.xp[0][m2][cb + j] = (cb + j == myidx) ? 0x3C00u : 0u;
    }
    __syncthreads();
  }
}

extern "C" void kernel_launch(void* const* d_in, const int* in_sizes, int n_in,
                              void* d_out, int out_size, void* d_ws, size_t ws_size,
                              hipStream_t stream) {
  (void)in_sizes; (void)n_in; (void)d_ws; (void)ws_size; (void)out_size;
  const float* x      = (const float*)d_in[0];
  const float* enc_Wx = (const float*)d_in[1];
  const float* enc_bx = (const float*)d_in[2];
  const float* enc_Wh = (const float*)d_in[3];
  // d_in[4] enc_Wy, d_in[5] enc_by: computed-but-discarded in the reference
  const float* dec_Wx = (const float*)d_in[6];
  const float* dec_bx = (const float*)d_in[7];
  const float* dec_Wh = (const float*)d_in[8];
  const float* dec_Wy = (const float*)d_in[9];
  const float* dec_by = (const float*)d_in[10];
  float* outp = (float*)d_out;

  seq2seq_kernel<<<NN / NB, NTH, 0, stream>>>(
      x, enc_Wx, enc_bx, enc_Wh, dec_Wx, dec_bx, dec_Wh, dec_Wy, dec_by, outp);
}

// Round 5
// 1178.508 us; speedup vs baseline: 1.0561x; 1.0561x over previous
//
#include <hip/hip_runtime.h>
#include <cstdint>
#include <cstddef>

#define TT 256
#define NN 4096
#define CC 12
#define DD 256
#define KD 12
#define NB 16
#define NTH 512
#define HS 264   // halfs per h row: 256 + 8 pad (rows 16B-aligned)
#define XS 40    // halfs per x row: 32 + 8 pad

typedef _Float16 half8 __attribute__((ext_vector_type(8)));
typedef float f32x4 __attribute__((ext_vector_type(4)));
#define MFMA __builtin_amdgcn_mfma_f32_16x16x32_f16

struct FalseC { static constexpr bool value = false; };
struct TrueC  { static constexpr bool value = true;  };

// LDS: 33,792 (h planes) + 5,120 (x planes) + 16,384 (wy) = 55,296 B
struct alignas(16) SM {
  _Float16 hhi[2][NB][HS];   // h hi plane, double-buffered
  _Float16 hlo[2][NB][HS];   // h lo plane
  _Float16 xhi[2][NB][XS];   // x_t / one-hot sos, hi plane, cols 12..31 zero
  _Float16 xlo[2][NB][XS];   // x lo plane (unused by decoder)
  half8 wyhi[8][64];         // dec_Wy B-fragments, hi plane [chunk][lane]
  half8 wylo[8][64];         // lo plane
};

__device__ __forceinline__ void split8(const float* w, half8& hi, half8& lo) {
  #pragma unroll
  for (int j = 0; j < 8; ++j) {
    _Float16 h = (_Float16)w[j];
    hi[j] = h;
    lo[j] = (_Float16)(w[j] - (float)h);
  }
}

__global__ __launch_bounds__(NTH, 2)
void seq2seq_kernel(const float* __restrict__ x,
                    const float* __restrict__ enc_Wx,
                    const float* __restrict__ enc_bx,
                    const float* __restrict__ enc_Wh,
                    const float* __restrict__ dec_Wx,
                    const float* __restrict__ dec_bx,
                    const float* __restrict__ dec_Wh,
                    const float* __restrict__ dec_Wy,
                    const float* __restrict__ dec_by,
                    float* __restrict__ out)
{
  __shared__ SM sm;
  const int tid  = (int)threadIdx.x;
  const int wid  = tid >> 6;
  const int lane = tid & 63;
  const int l15  = lane & 15;
  const int quad = lane >> 4;
  const int n0   = (int)blockIdx.x * NB;

  half8 Whi[2][8], Wlo[2][8];   // Wh B-fragments (AGPR-resident), persistent
  half8 Xhi[2], Xlo[2];         // Wx B-fragments (K=32 padded chunk)
  float bxr[2];

  auto loadWh = [&](const float* __restrict__ W) {
    #pragma unroll
    for (int tt = 0; tt < 2; ++tt) {
      const int n = (wid * 2 + tt) * 16 + l15;
      #pragma unroll
      for (int c = 0; c < 8; ++c) {
        float w[8];
        const float* p = W + (size_t)n * DD + c * 32 + quad * 8;
        *(float4*)&w[0] = *(const float4*)p;
        *(float4*)&w[4] = *(const float4*)(p + 4);
        split8(w, Whi[tt][c], Wlo[tt][c]);
      }
    }
  };
  auto loadWx = [&](const float* __restrict__ Wx) {
    #pragma unroll
    for (int tt = 0; tt < 2; ++tt) {
      const int n = (wid * 2 + tt) * 16 + l15;
      float w[8];
      #pragma unroll
      for (int j = 0; j < 8; ++j) {
        const int k = quad * 8 + j;
        w[j] = (k < CC) ? Wx[(size_t)n * CC + k] : 0.f;
      }
      split8(w, Xhi[tt], Xlo[tt]);
    }
  };
  auto loadBx = [&](const float* __restrict__ bx) {
    #pragma unroll
    for (int tt = 0; tt < 2; ++tt) bxr[tt] = bx[(wid * 2 + tt) * 16 + l15];
  };

  // One RNN step. DEC skips the x-lo plane (one-hot sos is exact in hi).
  auto stepA = [&](auto DEC_c, int rdbuf, int xslot, bool prefetch,
                   const float* __restrict__ xg) {
    constexpr bool DEC = decltype(DEC_c)::value;
    float pf[3];
    if (prefetch && wid == 1) {
      #pragma unroll
      for (int j = 0; j < 3; ++j) pf[j] = xg[lane + 64 * j];
    }
    f32x4 aA0 = {0.f,0.f,0.f,0.f}, aA1 = {0.f,0.f,0.f,0.f};
    f32x4 aB0 = {0.f,0.f,0.f,0.f}, aB1 = {0.f,0.f,0.f,0.f};

    // x-term first: fills MFMA pipe while h reads stream in
    {
      const half8 xh = *(const half8*)&sm.xhi[xslot][l15][quad * 8];
      aA0 = MFMA(xh, Xhi[0], aA0, 0, 0, 0);
      aA1 = MFMA(xh, Xhi[1], aA1, 0, 0, 0);
      if constexpr (!DEC) {
        const half8 xl = *(const half8*)&sm.xlo[xslot][l15][quad * 8];
        aB0 = MFMA(xl, Xhi[0], aB0, 0, 0, 0);
        aB1 = MFMA(xl, Xhi[1], aB1, 0, 0, 0);
      }
      aB0 = MFMA(xh, Xlo[0], aB0, 0, 0, 0);
      aB1 = MFMA(xh, Xlo[1], aB1, 0, 0, 0);
    }
    const _Float16* hh = &sm.hhi[rdbuf][l15][0];  // A row m = lane&15
    const _Float16* hl = &sm.hlo[rdbuf][l15][0];
    #pragma unroll
    for (int c = 0; c < 8; ++c) {
      const half8 ahi = *(const half8*)(hh + c * 32 + quad * 8);
      const half8 alo = *(const half8*)(hl + c * 32 + quad * 8);
      aA0 = MFMA(ahi, Whi[0][c], aA0, 0, 0, 0);
      aA1 = MFMA(ahi, Whi[1][c], aA1, 0, 0, 0);
      aB0 = MFMA(alo, Whi[0][c], aB0, 0, 0, 0);
      aB1 = MFMA(alo, Whi[1][c], aB1, 0, 0, 0);
      aA0 = MFMA(ahi, Wlo[0][c], aA0, 0, 0, 0);
      aA1 = MFMA(ahi, Wlo[1][c], aA1, 0, 0, 0);
    }
    // epilogue: merge + bias + relu + hi/lo split, write new h planes
    const int wb = rdbuf ^ 1;
    #pragma unroll
    for (int r = 0; r < 4; ++r) {
      const int m = quad * 4 + r;
      const float v0 = fmaxf(aA0[r] + aB0[r] + bxr[0], 0.f);
      const float v1 = fmaxf(aA1[r] + aB1[r] + bxr[1], 0.f);
      const _Float16 h0 = (_Float16)v0, h1 = (_Float16)v1;
      sm.hhi[wb][m][(wid * 2 + 0) * 16 + l15] = h0;
      sm.hlo[wb][m][(wid * 2 + 0) * 16 + l15] = (_Float16)(v0 - (float)h0);
      sm.hhi[wb][m][(wid * 2 + 1) * 16 + l15] = h1;
      sm.hlo[wb][m][(wid * 2 + 1) * 16 + l15] = (_Float16)(v1 - (float)h1);
    }
    if (prefetch && wid == 1) {
      #pragma unroll
      for (int j = 0; j < 3; ++j) {
        const int i = lane + 64 * j;
        const float v = pf[j];
        const _Float16 h = (_Float16)v;
        sm.xhi[xslot ^ 1][i / CC][i % CC] = h;
        sm.xlo[xslot ^ 1][i / CC][i % CC] = (_Float16)(v - (float)h);
      }
    }
  };

  // ---------------- init ----------------
  {
    unsigned* z;
    z = (unsigned*)&sm.hhi[0][0][0];
    for (int i = tid; i < NB * HS / 2; i += NTH) z[i] = 0u;
    z = (unsigned*)&sm.hlo[0][0][0];
    for (int i = tid; i < NB * HS / 2; i += NTH) z[i] = 0u;
    z = (unsigned*)&sm.xhi[0][0][0];
    for (int i = tid; i < 2 * NB * XS / 2; i += NTH) z[i] = 0u;
    z = (unsigned*)&sm.xlo[0][0][0];
    for (int i = tid; i < 2 * NB * XS / 2; i += NTH) z[i] = 0u;
  }
  loadWh(enc_Wh);
  loadWx(enc_Wx);
  loadBx(enc_bx);
  __syncthreads();
  if (tid < NB * CC) {  // stage x_0
    const float v = x[(size_t)n0 * CC + tid];
    const _Float16 h = (_Float16)v;
    sm.xhi[0][tid / CC][tid % CC] = h;
    sm.xlo[0][tid / CC][tid % CC] = (_Float16)(v - (float)h);
  }
  __syncthreads();

  // ---------------- encoder: 1 barrier/step ----------------
  for (int t = 0; t < TT; ++t) {
    stepA(FalseC{}, t & 1, t & 1, t + 1 < TT,
          x + ((size_t)(t + 1) * NN + n0) * CC);
    __syncthreads();
  }
  // encoder final h now in planes[0]

  // ---------------- decoder setup ----------------
  loadWh(dec_Wh);
  loadWx(dec_Wx);
  loadBx(dec_bx);
  const float byv = (l15 < KD) ? dec_by[l15] : 0.f;
  {  // stage dec_Wy fragments (B[k][n]: n=lane&15, k=chunk*32+quad*8+j)
    const int c = tid >> 6, ln = tid & 63, q2 = ln >> 4, n = ln & 15;
    float w[8];
    if (n < KD) {
      const float* p = dec_Wy + (size_t)n * DD + c * 32 + q2 * 8;
      *(float4*)&w[0] = *(const float4*)p;
      *(float4*)&w[4] = *(const float4*)(p + 4);
    } else {
      #pragma unroll
      for (int j = 0; j < 8; ++j) w[j] = 0.f;
    }
    half8 hi, lo;
    split8(w, hi, lo);
    sm.wyhi[c][ln] = hi;
    sm.wylo[c][ln] = lo;
  }
  if (wid == 0) {  // sos one-hot: column CC-2 = 10 (covers cols 0..31 incl. stale x)
    const int m2 = lane >> 2, cb = (lane & 3) * 8;
    #pragma unroll
    for (int j = 0; j < 8; ++j)
      sm.xhi[0][m2][cb + j] = (cb + j == 10) ? (_Float16)1.0f : (_Float16)0.0f;
  }
  __syncthreads();

  // ---------------- decoder: 2 barriers/step ----------------
  for (int t = 0; t < TT; ++t) {
    stepA(TrueC{}, t & 1, 0, false, x);
    __syncthreads();
    if (wid == 0) {
      // y = h_new @ Wy^T + by  (single-wave MFMA, 3 independent chains)
      f32x4 yh = {0.f,0.f,0.f,0.f}, yl = {0.f,0.f,0.f,0.f}, yw = {0.f,0.f,0.f,0.f};
      const int nb = (t & 1) ^ 1;
      const _Float16* hh = &sm.hhi[nb][l15][0];
      const _Float16* hl = &sm.hlo[nb][l15][0];
      #pragma unroll
      for (int c = 0; c < 8; ++c) {
        const half8 ahi = *(const half8*)(hh + c * 32 + quad * 8);
        const half8 alo = *(const half8*)(hl + c * 32 + quad * 8);
        const half8 bh = sm.wyhi[c][lane];
        const half8 bl = sm.wylo[c][lane];
        yh = MFMA(ahi, bh, yh, 0, 0, 0);
        yl = MFMA(alo, bh, yl, 0, 0, 0);
        yw = MFMA(ahi, bl, yw, 0, 0, 0);
      }
      float vr[4];
      int idxr[4];
      #pragma unroll
      for (int r = 0; r < 4; ++r) {
        const float yv = yh[r] + yl[r] + yw[r] + byv;
        const int m = quad * 4 + r;
        if (l15 < KD) out[((size_t)t * NN + n0 + m) * KD + l15] = yv;
        vr[r] = (l15 < KD) ? yv : -1e30f;
        idxr[r] = l15;
      }
      // argmax across the 16-lane n-groups, first-max tie-break (np semantics)
      #pragma unroll
      for (int d = 1; d < 16; d <<= 1) {
        #pragma unroll
        for (int r = 0; r < 4; ++r) {
          const float ov = __shfl_xor(vr[r], d);
          const int oi = __shfl_xor(idxr[r], d);
          const bool take = (ov > vr[r]) || (ov == vr[r] && oi < idxr[r]);
          vr[r] = take ? ov : vr[r];
          idxr[r] = take ? oi : idxr[r];
        }
      }
      // redistribute idx[m] to one-hot writers: writer lane covers row m2=lane>>2
      const int src = (lane >> 4) << 4;
      const int g0 = __shfl(idxr[0], src);
      const int g1 = __shfl(idxr[1], src);
      const int g2 = __shfl(idxr[2], src);
      const int g3 = __shfl(idxr[3], src);
      const int rr = (lane >> 2) & 3;
      const int myidx = rr == 0 ? g0 : rr == 1 ? g1 : rr == 2 ? g2 : g3;
      const int m2 = lane >> 2, cb = (lane & 3) * 8;
      #pragma unroll
      for (int j = 0; j < 8; ++j)
        sm.xhi[0][m2][cb + j] = (cb + j == myidx) ? (_Float16)1.0f : (_Float16)0.0f;
    }
    __syncthreads();
  }
}

extern "C" void kernel_launch(void* const* d_in, const int* in_sizes, int n_in,
                              void* d_out, int out_size, void* d_ws, size_t ws_size,
                              hipStream_t stream) {
  (void)in_sizes; (void)n_in; (void)d_ws; (void)ws_size; (void)out_size;
  const float* x      = (const float*)d_in[0];
  const float* enc_Wx = (const float*)d_in[1];
  const float* enc_bx = (const float*)d_in[2];
  const float* enc_Wh = (const float*)d_in[3];
  // d_in[4] enc_Wy, d_in[5] enc_by: computed-but-discarded in the reference
  const float* dec_Wx = (const float*)d_in[6];
  const float* dec_bx = (const float*)d_in[7];
  const float* dec_Wh = (const float*)d_in[8];
  const float* dec_Wy = (const float*)d_in[9];
  const float* dec_by = (const float*)d_in[10];
  float* outp = (float*)d_out;

  seq2seq_kernel<<<NN / NB, NTH, 0, stream>>>(
      x, enc_Wx, enc_bx, enc_Wh, dec_Wx, dec_bx, dec_Wh, dec_Wy, dec_by, outp);
}